// Round 4
// baseline (3618.262 us; speedup 1.0000x reference)
//
#include <hip/hip_runtime.h>
#include <hip/hip_fp16.h>
#include <stdint.h>

#define NB   64      // batch
#define NT   2048    // time steps
#define NF   256     // input features
#define NH   256     // hidden
#define NG   768     // 3*NH

typedef unsigned int u32;

__device__ __forceinline__ u32 packpair(float a, float b) {
    return __builtin_bit_cast(u32, __builtin_amdgcn_cvt_pkrtz(a, b));   // v_cvt_pkrtz_f16_f32
}
__device__ __forceinline__ u32 hfma2u(u32 w, u32 h, u32 acc) {        // v_pk_fma_f16 (full rate)
    __half2 r = __hfma2(__builtin_bit_cast(__half2, w),
                        __builtin_bit_cast(__half2, h),
                        __builtin_bit_cast(__half2, acc));
    return __builtin_bit_cast(u32, r);
}
__device__ __forceinline__ float pairsum(u32 a) {
    __half2 h = __builtin_bit_cast(__half2, a);
    return __low2float(h) + __high2float(h);
}
// sum across the 4 lanes of a quad — 2 DPP adds
__device__ __forceinline__ float quad_sum(float v) {
    int i = __builtin_bit_cast(int, v);
    v += __builtin_bit_cast(float, __builtin_amdgcn_update_dpp(0, i, 0xB1, 0xF, 0xF, true)); // [1,0,3,2]
    i = __builtin_bit_cast(int, v);
    v += __builtin_bit_cast(float, __builtin_amdgcn_update_dpp(0, i, 0x4E, 0xF, 0xF, true)); // [2,3,0,1]
    return v;
}

// ================= Kernel 1: xi = x @ Wi  (pk_fma inner, f16 out) ==========
__global__ __launch_bounds__(256, 2) void xi_gemm(const float* __restrict__ x,
                                                  const float* __restrict__ Wi,
                                                  __half* __restrict__ xi) {
    __shared__ u32 xs2[32][128];           // xs2[r][p] = (x[r][2p], x[r][2p+1]) f16
    const int tid = threadIdx.x;
    const int r0  = blockIdx.x * 32;
    {
        const int hi = tid >> 7, lo = tid & 127;
        #pragma unroll
        for (int rr = 0; rr < 16; ++rr) {
            const int r = rr * 2 + hi;
            const float2 v = *(const float2*)&x[(size_t)(r0 + r) * NF + lo * 2];
            xs2[r][lo] = packpair(v.x, v.y);
        }
    }
    __syncthreads();

    u32 acc2[32][3];                       // f16-pair accumulators (even/odd k)
    #pragma unroll
    for (int r = 0; r < 32; ++r) { acc2[r][0] = 0; acc2[r][1] = 0; acc2[r][2] = 0; }

    for (int kp2 = 0; kp2 < 64; ++kp2) {   // 4 K-rows per iteration
        const int k = kp2 * 4;
        u32 wA[3], wB[3];
        #pragma unroll
        for (int j = 0; j < 3; ++j) {
            const float* wp = &Wi[(size_t)k * NG + j * 256 + tid];
            wA[j] = packpair(wp[0],              wp[NG]);
            wB[j] = packpair(wp[2 * (size_t)NG], wp[3 * (size_t)NG]);
        }
        #pragma unroll
        for (int r = 0; r < 32; ++r) {
            const uint2 xv = *(const uint2*)&xs2[r][kp2 * 2];   // uniform -> broadcast
            #pragma unroll
            for (int j = 0; j < 3; ++j)
                acc2[r][j] = hfma2u(wB[j], xv.y, hfma2u(wA[j], xv.x, acc2[r][j]));
        }
    }

    #pragma unroll
    for (int r = 0; r < 32; ++r)
        #pragma unroll
        for (int j = 0; j < 3; ++j)
            xi[(size_t)(r0 + r) * NG + j * 256 + tid] = __float2half(pairsum(acc2[r][j]));
}

// ================= Kernel 2: recurrent scan — ONE block per batch ==========
// 1024 threads = (u in [0,256), kc = tid&3). Thread owns the 3 gate columns
// {u, u+256, u+512} over k-chunk [64kc, 64kc+64): 96 packed-f16 Wh VGPRs.
// After 2-DPP quad reduce every quad has its unit's full (r,z,n) -> gates
// in-register (no LDS roundtrip). Double-buffered h replicas -> ONE barrier
// per step. Replica stride 136 u32: reads kc -> banks 8kc..8kc+7 (disjoint),
// writes tile all 32 banks.
__global__ __launch_bounds__(1024, 1) void gru_rec(
        const float* __restrict__ carry,
        const __half* __restrict__ xi,
        const float* __restrict__ Wh,
        const float* __restrict__ bh,
        float* __restrict__ out_carry,
        float* __restrict__ out_hidden) {
    __shared__ u32 hsh[2][4][136];     // [buf][replica][pairs(128)+pad]

    const int tid = threadIdx.x;
    const int b   = blockIdx.x;
    const int u   = tid >> 2;          // unit 0..255
    const int kc  = tid & 3;           // k-chunk 0..3
    const int k0  = kc * 64;

    // -------- register-stationary Wh: wh2[j][p] = (Wh[k0+2p][col_j], Wh[k0+2p+1][col_j])
    u32 wh2[3][32];
    #pragma unroll
    for (int j = 0; j < 3; ++j) {
        const float* wp = &Wh[(size_t)k0 * NG + j * 256 + u];
        #pragma unroll
        for (int p = 0; p < 32; ++p) {
            wh2[j][p] = packpair(wp[0], wp[NG]);
            wp += 2 * (size_t)NG;
        }
    }
    const float br = bh[u], bz = bh[256 + u], bn = bh[512 + u];

    float hreg = carry[(size_t)b * NH + u];
    ((__half*)&hsh[0][kc][0])[u] = __float2half(hreg);

    const __half* xp = xi + (size_t)b * NT * NG;
    __half xr = xp[u], xz = xp[256 + u], xn = xp[512 + u];
    const __half* xq = xp + NG;                    // prefetch cursor (t+1)
    float* op = out_hidden + (size_t)b * NT * NH + u;

    __syncthreads();

#define FMA3(p, hc) { a0 = hfma2u(wh2[0][p], hc, a0); \
                      a1 = hfma2u(wh2[1][p], hc, a1); \
                      a2 = hfma2u(wh2[2][p], hc, a2); }

    for (int t = 0; t < NT; ++t) {
        const uint4* hp4 = (const uint4*)&hsh[t & 1][kc][kc * 32];
        u32 a0 = 0, a1 = 0, a2 = 0;
        #pragma unroll
        for (int ph = 0; ph < 4; ++ph) {           // 4 phases x 8 pairs, capped live h regs
            const uint4 h0 = hp4[2 * ph], h1 = hp4[2 * ph + 1];
            FMA3(8 * ph + 0, h0.x); FMA3(8 * ph + 1, h0.y);
            FMA3(8 * ph + 2, h0.z); FMA3(8 * ph + 3, h0.w);
            FMA3(8 * ph + 4, h1.x); FMA3(8 * ph + 5, h1.y);
            FMA3(8 * ph + 6, h1.z); FMA3(8 * ph + 7, h1.w);
            asm volatile("" ::: "memory");         // don't hoist next phase's ds_reads
        }
        float s0 = quad_sum(pairsum(a0));
        float s1 = quad_sum(pairsum(a1));
        float s2 = quad_sum(pairsum(a2));

        // gates: all 4 quad lanes redundantly (identical f32 ops -> identical results)
        const float rg = 1.f / (1.f + __expf(-(__half2float(xr) + s0 + br)));
        const float zg = 1.f / (1.f + __expf(-(__half2float(xz) + s1 + bz)));
        const float tt = __half2float(xn) + rg * (s2 + bn);
        const float ng = 1.f - 2.f / (__expf(2.f * tt) + 1.f);
        const float hn = (1.f - zg) * ng + zg * hreg;
        hreg = hn;

        if (kc == 0) *op = hn;
        op += NH;
        ((__half*)&hsh[(t + 1) & 1][kc][0])[u] = __float2half(hn);   // lane kc -> replica kc

        if (t + 1 < NT) {                          // prefetch next xi (hidden under next dot)
            xr = xq[u]; xz = xq[256 + u]; xn = xq[512 + u];
            xq += NG;
        }
        __syncthreads();
    }
#undef FMA3

    if (kc == 0) out_carry[(size_t)b * NH + u] = hreg;
}

// ================= host =================
extern "C" void kernel_launch(void* const* d_in, const int* in_sizes, int n_in,
                              void* d_out, int out_size, void* d_ws, size_t ws_size,
                              hipStream_t stream) {
    const float* carry = (const float*)d_in[0];
    const float* x     = (const float*)d_in[1];
    const float* Wi    = (const float*)d_in[2];
    const float* Wh    = (const float*)d_in[3];
    const float* bh    = (const float*)d_in[4];

    float* out_carry  = (float*)d_out;
    float* out_hidden = out_carry + (size_t)NB * NH;

    __half* xi = (__half*)d_ws;   // 64*2048*768*2 B = 201.3 MB (fits, proven round 1)

    xi_gemm<<<dim3(NB * NT / 32), dim3(256), 0, stream>>>(x, Wi, xi);
    gru_rec<<<dim3(NB), dim3(1024), 0, stream>>>(carry, xi, Wh, bh,
                                                 out_carry, out_hidden);
}

// Round 5
// 3421.893 us; speedup vs baseline: 1.0574x; 1.0574x over previous
//
#include <hip/hip_runtime.h>
#include <hip/hip_fp16.h>
#include <stdint.h>

#define NB   64      // batch
#define NT   2048    // time steps
#define NF   256     // input features
#define NH   256     // hidden
#define NG   768     // 3*NH

typedef unsigned int u32;
typedef _Float16 f16;
typedef f16 half2v __attribute__((ext_vector_type(2)));

__device__ __forceinline__ u32 packpair(float a, float b) {
    return __builtin_bit_cast(u32, __builtin_amdgcn_cvt_pkrtz(a, b));   // v_cvt_pkrtz_f16_f32
}
__device__ __forceinline__ float fdot2u(u32 w, u32 h, float acc) {      // f32-acc dot2
#if __has_builtin(__builtin_amdgcn_fdot2)
    return __builtin_amdgcn_fdot2(__builtin_bit_cast(half2v, w),
                                  __builtin_bit_cast(half2v, h), acc, false);
#else
    half2v wv = __builtin_bit_cast(half2v, w), hv = __builtin_bit_cast(half2v, h);
    return fmaf((float)wv[1], (float)hv[1], fmaf((float)wv[0], (float)hv[0], acc));
#endif
}
__device__ __forceinline__ u32 hfma2u(u32 w, u32 h, u32 acc) {          // v_pk_fma_f16
    __half2 r = __hfma2(__builtin_bit_cast(__half2, w),
                        __builtin_bit_cast(__half2, h),
                        __builtin_bit_cast(__half2, acc));
    return __builtin_bit_cast(u32, r);
}
__device__ __forceinline__ float pairsum(u32 a) {
    __half2 h = __builtin_bit_cast(__half2, a);
    return __low2float(h) + __high2float(h);
}
// sum across the 4 lanes of a quad — 2 DPP adds
__device__ __forceinline__ float quad_sum(float v) {
    int i = __builtin_bit_cast(int, v);
    v += __builtin_bit_cast(float, __builtin_amdgcn_update_dpp(0, i, 0xB1, 0xF, 0xF, true)); // [1,0,3,2]
    i = __builtin_bit_cast(int, v);
    v += __builtin_bit_cast(float, __builtin_amdgcn_update_dpp(0, i, 0x4E, 0xF, 0xF, true)); // [2,3,0,1]
    return v;
}

// ================= Kernel 1: xi = x @ Wi  (round-3 proven: fdot2, f32 acc) ==
__global__ __launch_bounds__(256, 2) void xi_gemm(const float* __restrict__ x,
                                                  const float* __restrict__ Wi,
                                                  __half* __restrict__ xi) {
    __shared__ u32 xs2[32][128];           // xs2[r][p] = (x[r][2p], x[r][2p+1]) f16
    const int tid = threadIdx.x;
    const int r0  = blockIdx.x * 32;
    {
        const int hi = tid >> 7, lo = tid & 127;
        #pragma unroll
        for (int rr = 0; rr < 16; ++rr) {
            const int r = rr * 2 + hi;
            const float2 v = *(const float2*)&x[(size_t)(r0 + r) * NF + lo * 2];
            xs2[r][lo] = packpair(v.x, v.y);
        }
    }
    __syncthreads();

    float acc[32][3];
    #pragma unroll
    for (int r = 0; r < 32; ++r) { acc[r][0] = 0.f; acc[r][1] = 0.f; acc[r][2] = 0.f; }

    for (int kp2 = 0; kp2 < 64; ++kp2) {   // 4 K-rows per iteration
        const int k = kp2 * 4;
        u32 wA[3], wB[3];
        #pragma unroll
        for (int j = 0; j < 3; ++j) {
            const float* wp = &Wi[(size_t)k * NG + j * 256 + tid];
            wA[j] = packpair(wp[0],              wp[NG]);
            wB[j] = packpair(wp[2 * (size_t)NG], wp[3 * (size_t)NG]);
        }
        #pragma unroll
        for (int r = 0; r < 32; ++r) {
            const uint2 xv = *(const uint2*)&xs2[r][kp2 * 2];   // uniform -> broadcast
            #pragma unroll
            for (int j = 0; j < 3; ++j)
                acc[r][j] = fdot2u(wB[j], xv.y, fdot2u(wA[j], xv.x, acc[r][j]));
        }
    }

    #pragma unroll
    for (int r = 0; r < 32; ++r)
        #pragma unroll
        for (int j = 0; j < 3; ++j)
            xi[(size_t)(r0 + r) * NG + j * 256 + tid] = __float2half(acc[r][j]);
}

// ================= Kernel 2: recurrent scan — ONE block per batch ==========
// 512 threads = (u2 in [0,128), kc = tid&3). Thread owns units {u2, u2+128}
// x 3 gates over k-chunk [64kc, 64kc+64): 192 packed-f16 Wh u32.
// 2 waves/SIMD -> 256-VGPR budget: weights stay ARCHITECTURAL (no AGPR
// shadow reads — round 4's regression). Quad reduce = 2 DPP adds; gates
// in-register; double-buffered h replicas -> ONE barrier/step.
__global__ __launch_bounds__(512, 2) void gru_rec(
        const float* __restrict__ carry,
        const __half* __restrict__ xi,
        const float* __restrict__ Wh,
        const float* __restrict__ bh,
        float* __restrict__ out_carry,
        float* __restrict__ out_hidden) {
    __shared__ u32 hsh[2][4][136];     // [buf][replica][128 pairs + pad]

    const int tid = threadIdx.x;
    const int b   = blockIdx.x;
    const int u2  = tid >> 2;          // 0..127 ; owns units u2 and u2+128
    const int kc  = tid & 3;           // k-chunk 0..3
    const int k0  = kc * 64;

    // ---- register-stationary Wh: wh2[uu][j][p] = packed (k0+2p, k0+2p+1)
    u32 wh2[2][3][32];
    #pragma unroll
    for (int uu = 0; uu < 2; ++uu)
        #pragma unroll
        for (int j = 0; j < 3; ++j) {
            const float* wp = &Wh[(size_t)k0 * NG + j * 256 + uu * 128 + u2];
            #pragma unroll
            for (int p = 0; p < 32; ++p) {
                wh2[uu][j][p] = packpair(wp[0], wp[NG]);
                wp += 2 * (size_t)NG;
            }
        }
    const float br0 = bh[u2],       bz0 = bh[256 + u2],       bn0 = bh[512 + u2];
    const float br1 = bh[128 + u2], bz1 = bh[384 + u2], bn1 = bh[640 + u2];

    float h0reg = carry[(size_t)b * NH + u2];
    float h1reg = carry[(size_t)b * NH + 128 + u2];
    ((__half*)&hsh[0][kc][0])[u2]       = __float2half(h0reg);
    ((__half*)&hsh[0][kc][0])[128 + u2] = __float2half(h1reg);

    const __half* xp = xi + (size_t)b * NT * NG;
    __half xr0 = xp[u2],       xz0 = xp[256 + u2],       xn0 = xp[512 + u2];
    __half xr1 = xp[128 + u2], xz1 = xp[384 + u2], xn1 = xp[640 + u2];
    const __half* xq = xp + NG;                 // prefetch cursor (t+1)

    __syncthreads();

#define FMA6(p, hc) { a00 = hfma2u(wh2[0][0][p], hc, a00);  \
                      a01 = hfma2u(wh2[0][1][p], hc, a01);  \
                      a02 = hfma2u(wh2[0][2][p], hc, a02);  \
                      a10 = hfma2u(wh2[1][0][p], hc, a10);  \
                      a11 = hfma2u(wh2[1][1][p], hc, a11);  \
                      a12 = hfma2u(wh2[1][2][p], hc, a12); }

    for (int t = 0; t < NT; ++t) {
        const uint4* hp4 = (const uint4*)&hsh[t & 1][kc][kc * 32];
        u32 a00 = 0, a01 = 0, a02 = 0, a10 = 0, a11 = 0, a12 = 0;
        #pragma unroll
        for (int ph = 0; ph < 4; ++ph) {        // 4 phases x 8 pairs: caps live h regs
            const uint4 hA = hp4[2 * ph], hB = hp4[2 * ph + 1];
            FMA6(8 * ph + 0, hA.x); FMA6(8 * ph + 1, hA.y);
            FMA6(8 * ph + 2, hA.z); FMA6(8 * ph + 3, hA.w);
            FMA6(8 * ph + 4, hB.x); FMA6(8 * ph + 5, hB.y);
            FMA6(8 * ph + 6, hB.z); FMA6(8 * ph + 7, hB.w);
            asm volatile("" ::: "memory");
        }
        const float s00 = quad_sum(pairsum(a00));
        const float s01 = quad_sum(pairsum(a01));
        const float s02 = quad_sum(pairsum(a02));
        const float s10 = quad_sum(pairsum(a10));
        const float s11 = quad_sum(pairsum(a11));
        const float s12 = quad_sum(pairsum(a12));

        // gates (all 4 quad lanes redundantly -> identical f32 results)
        const float rg0 = 1.f / (1.f + __expf(-(__half2float(xr0) + s00 + br0)));
        const float zg0 = 1.f / (1.f + __expf(-(__half2float(xz0) + s01 + bz0)));
        const float tt0 = __half2float(xn0) + rg0 * (s02 + bn0);
        const float ng0 = 1.f - 2.f / (__expf(2.f * tt0) + 1.f);
        const float hn0 = (1.f - zg0) * ng0 + zg0 * h0reg;
        const float rg1 = 1.f / (1.f + __expf(-(__half2float(xr1) + s10 + br1)));
        const float zg1 = 1.f / (1.f + __expf(-(__half2float(xz1) + s11 + bz1)));
        const float tt1 = __half2float(xn1) + rg1 * (s12 + bn1);
        const float ng1 = 1.f - 2.f / (__expf(2.f * tt1) + 1.f);
        const float hn1 = (1.f - zg1) * ng1 + zg1 * h1reg;
        h0reg = hn0; h1reg = hn1;

        if (kc == 0) {
            float* o = out_hidden + ((size_t)b * NT + t) * NH + u2;
            o[0] = hn0; o[128] = hn1;
        }
        ((__half*)&hsh[(t + 1) & 1][kc][0])[u2]       = __float2half(hn0);
        ((__half*)&hsh[(t + 1) & 1][kc][0])[128 + u2] = __float2half(hn1);

        if (t + 1 < NT) {                      // prefetch next xi
            xr0 = xq[u2];       xz0 = xq[256 + u2];       xn0 = xq[512 + u2];
            xr1 = xq[128 + u2]; xz1 = xq[384 + u2]; xn1 = xq[640 + u2];
            xq += NG;
        }
        __syncthreads();
    }
#undef FMA6

    if (kc == 0) {
        out_carry[(size_t)b * NH + u2]       = h0reg;
        out_carry[(size_t)b * NH + 128 + u2] = h1reg;
    }
}

// ================= host =================
extern "C" void kernel_launch(void* const* d_in, const int* in_sizes, int n_in,
                              void* d_out, int out_size, void* d_ws, size_t ws_size,
                              hipStream_t stream) {
    const float* carry = (const float*)d_in[0];
    const float* x     = (const float*)d_in[1];
    const float* Wi    = (const float*)d_in[2];
    const float* Wh    = (const float*)d_in[3];
    const float* bh    = (const float*)d_in[4];

    float* out_carry  = (float*)d_out;
    float* out_hidden = out_carry + (size_t)NB * NH;

    __half* xi = (__half*)d_ws;   // 64*2048*768*2 B = 201.3 MB (fits, proven)

    xi_gemm<<<dim3(NB * NT / 32), dim3(256), 0, stream>>>(x, Wi, xi);
    gru_rec<<<dim3(NB), dim3(512), 0, stream>>>(carry, xi, Wh, bh,
                                                out_carry, out_hidden);
}